// Round 5
// baseline (102490.063 us; speedup 1.0000x reference)
//
#include <hip/hip_runtime.h>
#include <stdint.h>

#define DEV __device__ __forceinline__

namespace {

constexpr int kT = 512, kB = 32, kF = 128, kHE = 512, kHD = 512, kA = 256;

typedef _Float16 f16;
typedef _Float16 h2 __attribute__((ext_vector_type(2)));
typedef _Float16 h4 __attribute__((ext_vector_type(4)));

// ---- workspace layout (float-unit offsets) ----
// R5: encoder reads eWih/eWhh fp32 directly (no ws copy) — full-fp32 encoder
// restores precision margin lost in R4 (f16 h-recurrence -> 9.8e-4 absmax,
// replay jitter pushed past 1.29e-3 threshold).
constexpr size_t oWdecC  = 0;                          // f16 [2048][1024] = [Wih_ctx | Wih_h+Whh]
constexpr size_t oWdWH   = oWdecC + 1048576;           // f16 [256][512]   = WdecW
constexpr size_t oEncSt  = oWdWH + 65536;              // f32 [32][512][512]
constexpr size_t oEncPr  = oEncSt + (size_t)kB*kT*kHE; // f32 [32*512][256]
constexpr size_t oHdec   = oEncPr + (size_t)kB*kT*kA;  // f32 [3][32][512]
constexpr size_t oCtx    = oHdec + 3ull*kB*kHD;        // f32 [3][32][512] (unnormalized, x kScale)
constexpr size_t oDen    = oCtx + 3ull*kB*kHE;         // f32 [3][32]
constexpr size_t oScp    = oDen + 96;                  // f32 [32][16][256]
constexpr size_t oEbias  = oScp + (size_t)kB*16*kA;    // 2048
constexpr size_t oDbias  = oEbias + 2048;              // 2048
constexpr size_t oAb2    = oDbias + 2048;              // 256
constexpr size_t oCtr    = oAb2 + 256;                 // int area: [0]=abort, [64..575]=slotC, [576..1087]=slotA, [1088..1599]=slotB

constexpr float kScale = 1.0f/64.0f;

DEV float frcp(float x){ return __builtin_amdgcn_rcpf(x); }
DEV float fsig(float x){ return frcp(1.f + __expf(-x)); }
DEV float ftanh(float x){ return 1.f - 2.f*frcp(__expf(2.f*x) + 1.f); }

DEV float fdot2(h2 a, h2 b, float c){
#if __has_builtin(__builtin_amdgcn_fdot2)
  return __builtin_amdgcn_fdot2(a, b, c, false);
#else
  return c + (float)a.x*(float)b.x + (float)a.y*(float)b.y;
#endif
}

// relaxed agent-scope (MALL-coherent) accessors
DEV float ld_na(const float* p){ return __hip_atomic_load((float*)p, __ATOMIC_RELAXED, __HIP_MEMORY_SCOPE_AGENT); }
DEV void  st_na(float* p, float v){ __hip_atomic_store(p, v, __ATOMIC_RELAXED, __HIP_MEMORY_SCOPE_AGENT); }
DEV int   ld_ni(const int* p){ return __hip_atomic_load((int*)p, __ATOMIC_RELAXED, __HIP_MEMORY_SCOPE_AGENT); }
DEV void  st_ni(int* p, int v){ __hip_atomic_store(p, v, __ATOMIC_RELAXED, __HIP_MEMORY_SCOPE_AGENT); }

// distributed slot barrier: wave0 sweeps cnt slots (cnt<=256) with coalesced
// relaxed loads; other waves park at __syncthreads. No atomics, no shared hot word.
DEV void wait_slots(const int* base, int cnt, int tgt, int* abortf){
  if (threadIdx.x < 64){
    int lane = threadIdx.x;
    int guard = 0;
    for (;;){
      int ok = 1;
      for (int i = lane; i < cnt; i += 64) ok &= (ld_ni(base + i) >= tgt);
      if (__all(ok)) break;
      if (ld_ni(abortf) != 0) break;
      if (++guard > (1<<21)){ st_ni(abortf, 1); break; }
      __builtin_amdgcn_s_sleep(1);
    }
  }
  __syncthreads();
}
// arrive: __syncthreads drains all waves' outstanding stores (vmcnt) before the stamp issues
DEV void stamp_slot(int* slot, int v){
  __syncthreads();
  if (threadIdx.x == 0) st_ni(slot, v);
}

} // namespace

// ================= kernel 1: init / weight packing =================
__global__ __launch_bounds__(256) void init_kernel(
    const float* __restrict__ eBih, const float* __restrict__ eBhh,
    const float* __restrict__ WdecW, const float* __restrict__ WdecB, const float* __restrict__ attnB,
    const float* __restrict__ dWih, const float* __restrict__ dWhh,
    const float* __restrict__ dBih, const float* __restrict__ dBhh,
    float* __restrict__ ws)
{
  f16* wdecc = (f16*)(ws + oWdecC);
  f16* wdwh  = (f16*)(ws + oWdWH);
  float* hdec  = ws + oHdec;
  float* ctxb  = ws + oCtx;
  float* den   = ws + oDen;
  float* ebias = ws + oEbias;
  float* dbias = ws + oDbias;
  float* ab2w  = ws + oAb2;
  const int gid = blockIdx.x*256 + threadIdx.x;
  const int stride = gridDim.x*256;
  for (int i=gid; i<2048*1024; i+=stride){
    int col = i>>10, k = i&1023;
    float v = dWih[((size_t)col<<10) + k];
    if (k >= 512) v += dWhh[((size_t)col<<9) + (k-512)];
    wdecc[i] = (f16)v;
  }
  for (int i=gid; i<256*512; i+=stride)  wdwh[i] = (f16)WdecW[i];
  for (int i=gid; i<2048; i+=stride){ ebias[i] = eBih[i]+eBhh[i]; dbias[i] = dBih[i]+dBhh[i]; }
  for (int i=gid; i<256; i+=stride)  ab2w[i] = WdecB[i]+attnB[i];
  for (int i=gid; i<3*kB*kHE; i+=stride) ctxb[i] = 0.f;
  for (int i=gid; i<96; i+=stride) den[i] = 0.f;
  for (int i=gid; i<kB*kHD; i+=stride){
    int e = i & 511;
    float zi = dBih[e]+dBhh[e];
    float zg = dBih[1024+e]+dBhh[1024+e];
    float zo = dBih[1536+e]+dBhh[1536+e];
    float c0 = fsig(zi)*ftanh(zg);
    hdec[i] = fsig(zo)*ftanh(c0);   // buffer 0: initial decoder h
  }
}

// ================= kernel 2: encoder — 1 block per batch, full fp32, zero cross-block sync =================
__global__ __launch_bounds__(1024, 1) void enc_kernel(
    const float* __restrict__ x, const float* __restrict__ eWih,
    const float* __restrict__ eWhh, float* __restrict__ ws)
{
  const float* ebias = ws + oEbias;
  float* encst = ws + oEncSt;
  __shared__ float sx[128];
  __shared__ float sh[512];     // h state, fp32 (precision-critical recurrence)
  __shared__ float zs[2048];
  const int tid = threadIdx.x;
  const int b = blockIdx.x;
  const int col0 = tid, col1 = tid + 1024;
  const float4* wx0 = (const float4*)(eWih + (size_t)col0*kF);
  const float4* wx1 = (const float4*)(eWih + (size_t)col1*kF);
  const float4* wh0 = (const float4*)(eWhh + (size_t)col0*kHE);
  const float4* wh1 = (const float4*)(eWhh + (size_t)col1*kHE);
  const float b0v = ebias[col0], b1v = ebias[col1];
  if (tid < 512) sh[tid] = 0.f;
  float creg = 0.f;
  __syncthreads();
  for (int t=0; t<kT; ++t){
    if (tid < 32) ((float4*)sx)[tid] = ((const float4*)(x + ((size_t)b*kT + t)*kF))[tid];
    __syncthreads();
    float a0=0.f, a1=0.f;
    {
      const float4* sx4 = (const float4*)sx;
      #pragma unroll 8
      for (int q=0;q<32;++q){
        float4 xv = sx4[q]; float4 w = wx0[q]; float4 u = wx1[q];
        a0 += w.x*xv.x + w.y*xv.y + w.z*xv.z + w.w*xv.w;
        a1 += u.x*xv.x + u.y*xv.y + u.z*xv.z + u.w*xv.w;
      }
      const float4* sh4 = (const float4*)sh;
      #pragma unroll 8
      for (int q=0;q<128;++q){
        float4 hv = sh4[q]; float4 wa = wh0[q]; float4 wb = wh1[q];
        a0 += wa.x*hv.x + wa.y*hv.y + wa.z*hv.z + wa.w*hv.w;
        a1 += wb.x*hv.x + wb.y*hv.y + wb.z*hv.z + wb.w*hv.w;
      }
    }
    zs[col0] = a0 + b0v;
    zs[col1] = a1 + b1v;
    __syncthreads();
    if (tid < 512){
      float zi = zs[tid], zf = zs[512+tid], zg = zs[1024+tid], zo = zs[1536+tid];
      float c2 = fsig(zf)*creg + fsig(zi)*ftanh(zg);
      creg = c2;
      float h = fsig(zo)*ftanh(c2);
      encst[((size_t)b*kT + t)*kHE + tid] = h;
      sh[tid] = h;
    }
    __syncthreads();
  }
}

// ================= kernel 3: enc_proj = enc_states @ Wenc^T + b =================
__global__ __launch_bounds__(256) void encproj_kernel(
    const float* __restrict__ WencW, const float* __restrict__ WencB,
    float* __restrict__ ws)
{
  const float* encst = ws + oEncSt;
  float* encpr = ws + oEncPr;
  __shared__ float4 et[32][32];
  const int tid = threadIdx.x, bid = blockIdx.x;
  const int r0 = bid*32;
  float acc[32];
  #pragma unroll
  for (int i=0;i<32;++i) acc[i]=0.f;
  for (int kt=0; kt<4; ++kt){
    #pragma unroll
    for (int i2=0;i2<4;++i2){
      int q = tid + i2*256;
      int row = q>>5, qi = q&31;
      et[row][qi] = ((const float4*)(encst + ((size_t)(r0+row))*kHE + kt*128))[qi];
    }
    __syncthreads();
    const float4* wv = (const float4*)(WencW + (size_t)tid*kHE + kt*128);
    #pragma unroll 1
    for (int q=0;q<32;++q){
      float4 w = wv[q];
      #pragma unroll
      for (int i=0;i<32;++i){
        float4 e4 = et[i][q];
        acc[i] += e4.x*w.x + e4.y*w.y + e4.z*w.z + e4.w*w.w;
      }
    }
    __syncthreads();
  }
  float bb = WencB[tid];
  #pragma unroll
  for (int i=0;i<32;++i) encpr[((size_t)(r0+i))*kA + tid] = acc[i] + bb;
}

// ================= kernel 4: decoder — 512 blocks, slot-flag sync =================
namespace {
struct SA  { float h[32]; float sc[256]; float lw[32]; };
struct SC  { f16 xt[16][264]; float zb[128][2]; };
struct SmemDec {
  f16 epr[32][272];
  f16 est2[32][516];
  float v[256];
  union { SA a; SC c; } u;
};
}

__global__ __launch_bounds__(256, 2) void dec_kernel(
    const float* __restrict__ Vw, float* __restrict__ out, float* __restrict__ ws)
{
  __shared__ SmemDec sm;
  const int tid = threadIdx.x, bid = blockIdx.x;
  const f16* wdecc = (const f16*)(ws + oWdecC);
  const f16* wdwh  = (const f16*)(ws + oWdWH);
  const float* encst = ws + oEncSt;
  const float* encpr = ws + oEncPr;
  float* hdec = ws + oHdec;
  float* ctxb = ws + oCtx;
  float* den  = ws + oDen;
  float* scp  = ws + oScp;
  const float* dbias = ws + oDbias;
  const float* ab2w  = ws + oAb2;
  int* ctr   = (int*)(ws + oCtr);
  int* abortf = ctr;
  int* slotC = ctr + 64;     // [2][256] by (half, ecp)
  int* slotA = ctr + 576;    // [32][16] by (b, tc)
  int* slotB = ctr + 1088;   // [32][16] by (b, tc)

  const int bA = bid >> 4, tc = bid & 15, t0a = tc*32;      // A/B role
  const int half = bid >> 8, ecp = bid & 255, e0c = ecp*2;  // C role
  const int col_l = tid & 127, ksC = tid >> 7;
  const int e_lC = col_l & 1, gateC = (col_l>>1)&3, b_lC = col_l>>3;
  const int colC = gateC*kHD + e0c + e_lC;
  const f16* wrC = wdecc + (size_t)colC*1024;
  const int rowS = tid>>4, c16 = (tid&15)*16;

  // one-time LDS residents
  for (int i=tid; i<32*256; i+=256){
    int rr = i>>8, c = i&255;
    sm.epr[rr][c] = (f16)encpr[((size_t)bA*kT + t0a + rr)*kA + c];
  }
  for (int i=tid; i<32*512; i+=256){
    int rr = i>>9, c = i&511;
    sm.est2[rr][c] = (f16)encst[((size_t)bA*kT + t0a + rr)*kHE + c];
  }
  sm.v[tid] = Vw[tid];
  const float ab2r = ab2w[tid];
  float cregD=0, dbi=0, dbf=0, dbg=0, dbo=0;
  if (tid < 32){
    int e = e0c + (tid&1);
    dbi = dbias[e]; dbf = dbias[512+e]; dbg = dbias[1024+e]; dbo = dbias[1536+e];
    cregD = fsig(dbi)*ftanh(dbg);
  }
  __syncthreads();

  int r = 0;
  for (int t=0; t<kT; ++t){
    const int rn = (r==2) ? 0 : r+1;
    // ---- A: wait h producers (16 slots = 1 line), dscore partial ----
    wait_slots(slotC + (bA>>4)*256 + tc*16, 16, t, abortf);
    if (tid < 32) sm.u.a.h[tid] = ld_na(hdec + (size_t)r*kB*kHD + (size_t)bA*kHD + t0a + tid);
    __syncthreads();
    {
      const h4* wv = (const h4*)(wdwh + (size_t)tid*kHD + t0a);
      float sp = 0.f;
      #pragma unroll
      for (int q=0;q<8;++q){
        h4 w = wv[q];
        sp += (float)w.x*sm.u.a.h[q*4+0] + (float)w.y*sm.u.a.h[q*4+1]
            + (float)w.z*sm.u.a.h[q*4+2] + (float)w.w*sm.u.a.h[q*4+3];
      }
      st_na(&scp[((size_t)bA*16 + tc)*kA + tid], sp);
    }
    stamp_slot(&slotA[bA*16 + tc], t+1);
    // ---- B: wait 16 dscore partials, tanh-logits, exp, ctx partial ----
    wait_slots(slotA + bA*16, 16, t+1, abortf);
    {
      float sc = ab2r;
      #pragma unroll
      for (int j=0;j<16;++j) sc += ld_na(&scp[((size_t)bA*16 + j)*kA + tid]);
      sm.u.a.sc[tid] = sc;
    }
    __syncthreads();
    {
      const int tl = tid>>3, as = tid&7;
      float acc = 0.f;
      #pragma unroll
      for (int q=0;q<8;++q){
        int a0 = q*32 + as*4;
        h4 e4 = *(const h4*)(&sm.epr[tl][a0]);
        acc += sm.v[a0+0]*ftanh((float)e4.x + sm.u.a.sc[a0+0]);
        acc += sm.v[a0+1]*ftanh((float)e4.y + sm.u.a.sc[a0+1]);
        acc += sm.v[a0+2]*ftanh((float)e4.z + sm.u.a.sc[a0+2]);
        acc += sm.v[a0+3]*ftanh((float)e4.w + sm.u.a.sc[a0+3]);
      }
      acc += __shfl_down(acc, 4, 8);
      acc += __shfl_down(acc, 2, 8);
      acc += __shfl_down(acc, 1, 8);
      if (as == 0) sm.u.a.lw[tl] = __expf(acc) * kScale;
    }
    __syncthreads();
    {
      const int e0p = 2*tid;
      float c0=0.f, c1=0.f;
      #pragma unroll 8
      for (int j=0;j<32;++j){
        float w = sm.u.a.lw[j];
        h2 ev = *(const h2*)(&sm.est2[j][e0p]);
        c0 += w*(float)ev.x; c1 += w*(float)ev.y;
      }
      float* cdst = ctxb + (size_t)r*kB*kHE + (size_t)bA*kHE;
      atomicAdd(&cdst[e0p], c0);
      atomicAdd(&cdst[e0p+1], c1);
      if (tid == 0){
        float ds = 0.f;
        #pragma unroll
        for (int j=0;j<32;++j) ds += sm.u.a.lw[j];
        atomicAdd(&den[r*kB + bA], ds);
      }
      // zero rotation slice rn (last read at t-2): this block zeroes its own t-chunk columns
      if (tid < 32) st_na(ctxb + (size_t)rn*kB*kHE + (size_t)bA*kHE + t0a + tid, 0.f);
      if (tid == 0 && tc == 0) st_na(&den[rn*kB + bA], 0.f);
    }
    stamp_slot(&slotB[bA*16 + tc], t+1);
    // ---- C: wait all 256 ctx partials of this half, LSTM cell ----
    wait_slots(slotB + half*256, 256, t+1, abortf);
    {
      const float rv = frcp(ld_na(&den[r*kB + half*16 + b_lC]));
      float accc=0.f, acch=0.f;
      for (int kc=0; kc<4; ++kc){
        const float* src = ((kc<2) ? (ctxb + (size_t)r*kB*kHE) : (hdec + (size_t)r*kB*kHD))
                           + (size_t)(half*16 + rowS)*512 + (kc&1)*256 + c16;
        float f[16];
        #pragma unroll
        for (int j=0;j<16;++j) f[j] = ld_na(src+j);
        #pragma unroll
        for (int g=0; g<4; ++g){
          h4 hv; hv.x=(f16)f[4*g]; hv.y=(f16)f[4*g+1]; hv.z=(f16)f[4*g+2]; hv.w=(f16)f[4*g+3];
          *(h4*)(&sm.u.c.xt[rowS][c16 + 4*g]) = hv;
        }
        __syncthreads();
        const h4* wc = (const h4*)(wrC) + kc*64 + ksC*32;
        const h4* xv = (const h4*)(&sm.u.c.xt[b_lC][ksC*128]);
        float a = 0.f;
        #pragma unroll 8
        for (int q=0;q<32;++q){
          h4 w = wc[q], v = xv[q];
          a = fdot2(h2{w.x,w.y}, h2{v.x,v.y}, a);
          a = fdot2(h2{w.z,w.w}, h2{v.z,v.w}, a);
        }
        if (kc < 2) accc += a; else acch += a;
        __syncthreads();
      }
      sm.u.c.zb[col_l][ksC] = accc*rv + acch;
      __syncthreads();
      if (tid < 32){
        int base = (tid>>1)*8 + (tid&1);
        int e = e0c + (tid&1), b2 = half*16 + (tid>>1);
        float zi = sm.u.c.zb[base+0][0] + sm.u.c.zb[base+0][1] + dbi;
        float zf = sm.u.c.zb[base+2][0] + sm.u.c.zb[base+2][1] + dbf;
        float zg = sm.u.c.zb[base+4][0] + sm.u.c.zb[base+4][1] + dbg;
        float zo = sm.u.c.zb[base+6][0] + sm.u.c.zb[base+6][1] + dbo;
        float c2 = fsig(zf)*cregD + fsig(zi)*ftanh(zg);
        cregD = c2;
        float h = fsig(zo)*ftanh(c2);
        st_na(&hdec[(size_t)rn*kB*kHD + (size_t)b2*kHD + e], h);
        out[((size_t)b2*kT + t)*kHD + e] = h;
      }
    }
    stamp_slot(&slotC[half*256 + ecp], t+1);
    r = rn;
  }
}

extern "C" void kernel_launch(void* const* d_in, const int* in_sizes, int n_in,
                              void* d_out, int out_size, void* d_ws, size_t ws_size,
                              hipStream_t stream) {
  (void)in_sizes; (void)n_in; (void)out_size; (void)ws_size; // needs ws >= ~56 MB
  const float* x     = (const float*)d_in[0];
  const float* eWih  = (const float*)d_in[1];
  const float* eWhh  = (const float*)d_in[2];
  const float* eBih  = (const float*)d_in[3];
  const float* eBhh  = (const float*)d_in[4];
  const float* WencW = (const float*)d_in[5];
  const float* WencB = (const float*)d_in[6];
  const float* WdecW = (const float*)d_in[7];
  const float* WdecB = (const float*)d_in[8];
  const float* Vw    = (const float*)d_in[9];
  const float* attnB = (const float*)d_in[11];
  const float* dWih  = (const float*)d_in[12];
  const float* dWhh  = (const float*)d_in[13];
  const float* dBih  = (const float*)d_in[14];
  const float* dBhh  = (const float*)d_in[15];
  float* ws = (float*)d_ws;
  int* ctr = (int*)(ws + oCtr);
  hipMemsetAsync(ctr, 0, 8192, stream);
  hipLaunchKernelGGL(init_kernel, dim3(512), dim3(256), 0, stream,
                     eBih, eBhh, WdecW, WdecB, attnB, dWih, dWhh, dBih, dBhh, ws);
  hipLaunchKernelGGL(enc_kernel, dim3(32), dim3(1024), 0, stream, x, eWih, eWhh, ws);
  hipLaunchKernelGGL(encproj_kernel, dim3(512), dim3(256), 0, stream, WencW, WencB, ws);
  hipLaunchKernelGGL(dec_kernel, dim3(512), dim3(256), 0, stream, Vw, (float*)d_out, ws);
}

// Round 6
// 25505.449 us; speedup vs baseline: 4.0184x; 4.0184x over previous
//
#include <hip/hip_runtime.h>
#include <stdint.h>

#define DEV __device__ __forceinline__

namespace {

constexpr int kT = 512, kB = 32, kF = 128, kHE = 512, kHD = 512, kA = 256;

typedef _Float16 f16;
typedef _Float16 h2 __attribute__((ext_vector_type(2)));
typedef _Float16 h4 __attribute__((ext_vector_type(4)));

// ---- workspace layout (float-unit offsets) ----
constexpr size_t oWdecC  = 0;                          // f16 [2048][1024] = [Wih_ctx | Wih_h+Whh]
constexpr size_t oWdWH   = oWdecC + 1048576;           // f16 [256][512]   = WdecW
constexpr size_t oEncSt  = oWdWH + 65536;              // f32 [32][512][512]
constexpr size_t oEncPr  = oEncSt + (size_t)kB*kT*kHE; // f32 [32*512][256]
constexpr size_t oHdec   = oEncPr + (size_t)kB*kT*kA;  // f32 [3][32][512]
constexpr size_t oCtx    = oHdec + 3ull*kB*kHD;        // f32 [3][32][512] (unnormalized, x kScale)
constexpr size_t oDen    = oCtx + 3ull*kB*kHE;         // f32 [3][32]
constexpr size_t oScp    = oDen + 96;                  // f32 [32][16][256]
constexpr size_t oEbias  = oScp + (size_t)kB*16*kA;    // 2048
constexpr size_t oDbias  = oEbias + 2048;              // 2048
constexpr size_t oAb2    = oDbias + 2048;              // 256
constexpr size_t oCtr    = oAb2 + 256;                 // 2048 ints: [0]=abort, [64..575]=slotC,
                                                       // [576..1087]=slotA, [1088..1599]=slotB, [1600..1855]=slotE
constexpr size_t oHenc   = oCtr + 2048;                // f32 [2][32][512] encoder h double buffer

constexpr float kScale = 1.0f/64.0f;

DEV float frcp(float x){ return __builtin_amdgcn_rcpf(x); }
DEV float fsig(float x){ return frcp(1.f + __expf(-x)); }
DEV float ftanh(float x){ return 1.f - 2.f*frcp(__expf(2.f*x) + 1.f); }

DEV float fdot2(h2 a, h2 b, float c){
#if __has_builtin(__builtin_amdgcn_fdot2)
  return __builtin_amdgcn_fdot2(a, b, c, false);
#else
  return c + (float)a.x*(float)b.x + (float)a.y*(float)b.y;
#endif
}

// relaxed agent-scope (MALL-coherent) accessors
DEV float ld_na(const float* p){ return __hip_atomic_load((float*)p, __ATOMIC_RELAXED, __HIP_MEMORY_SCOPE_AGENT); }
DEV void  st_na(float* p, float v){ __hip_atomic_store(p, v, __ATOMIC_RELAXED, __HIP_MEMORY_SCOPE_AGENT); }
DEV int   ld_ni(const int* p){ return __hip_atomic_load((int*)p, __ATOMIC_RELAXED, __HIP_MEMORY_SCOPE_AGENT); }
DEV void  st_ni(int* p, int v){ __hip_atomic_store(p, v, __ATOMIC_RELAXED, __HIP_MEMORY_SCOPE_AGENT); }

// distributed slot barrier: wave0 sweeps cnt slots with coalesced relaxed loads
DEV void wait_slots(const int* base, int cnt, int tgt, int* abortf){
  if (threadIdx.x < 64){
    int lane = threadIdx.x;
    int guard = 0;
    for (;;){
      int ok = 1;
      for (int i = lane; i < cnt; i += 64) ok &= (ld_ni(base + i) >= tgt);
      if (__all(ok)) break;
      if (ld_ni(abortf) != 0) break;
      if (++guard > (1<<21)){ st_ni(abortf, 1); break; }
      __builtin_amdgcn_s_sleep(1);
    }
  }
  __syncthreads();
}
// arrive: __syncthreads drains each wave's outstanding stores before the stamp issues
DEV void stamp_slot(int* slot, int v){
  __syncthreads();
  if (threadIdx.x == 0) st_ni(slot, v);
}

} // namespace

// ================= kernel 1: init / weight packing =================
__global__ __launch_bounds__(256) void init_kernel(
    const float* __restrict__ eBih, const float* __restrict__ eBhh,
    const float* __restrict__ WdecW, const float* __restrict__ WdecB, const float* __restrict__ attnB,
    const float* __restrict__ dWih, const float* __restrict__ dWhh,
    const float* __restrict__ dBih, const float* __restrict__ dBhh,
    float* __restrict__ ws)
{
  f16* wdecc = (f16*)(ws + oWdecC);
  f16* wdwh  = (f16*)(ws + oWdWH);
  float* hdec  = ws + oHdec;
  float* ctxb  = ws + oCtx;
  float* den   = ws + oDen;
  float* ebias = ws + oEbias;
  float* dbias = ws + oDbias;
  float* ab2w  = ws + oAb2;
  float* henc  = ws + oHenc;
  const int gid = blockIdx.x*256 + threadIdx.x;
  const int stride = gridDim.x*256;
  for (int i=gid; i<2048*1024; i+=stride){
    int col = i>>10, k = i&1023;
    float v = dWih[((size_t)col<<10) + k];
    if (k >= 512) v += dWhh[((size_t)col<<9) + (k-512)];
    wdecc[i] = (f16)v;
  }
  for (int i=gid; i<256*512; i+=stride)  wdwh[i] = (f16)WdecW[i];
  for (int i=gid; i<2048; i+=stride){ ebias[i] = eBih[i]+eBhh[i]; dbias[i] = dBih[i]+dBhh[i]; }
  for (int i=gid; i<256; i+=stride)  ab2w[i] = WdecB[i]+attnB[i];
  for (int i=gid; i<3*kB*kHE; i+=stride) ctxb[i] = 0.f;
  for (int i=gid; i<2*kB*kHE; i+=stride) henc[i] = 0.f;
  for (int i=gid; i<96; i+=stride) den[i] = 0.f;
  for (int i=gid; i<kB*kHD; i+=stride){
    int e = i & 511;
    float zi = dBih[e]+dBhh[e];
    float zg = dBih[1024+e]+dBhh[1024+e];
    float zo = dBih[1536+e]+dBhh[1536+e];
    float c0 = fsig(zi)*ftanh(zg);
    hdec[i] = fsig(zo)*ftanh(c0);   // buffer 0: initial decoder h
  }
}

// ================= kernel 2: encoder — weight-stationary, slot-flag sync =================
// 256 blocks x 256 thr. block = (q = b-group of 8, j = e-slice of 8).
// W slab (4 gates x 8 e x 640) LDS-resident fp32 (loaded once: kills the R5
// 10.6 GB/dispatch per-step weight re-stream). Per step: gather h (MALL) + x,
// fp32 dot, pointwise LSTM (c in regs), publish 8-float h slice, stamp slot.
__global__ __launch_bounds__(256, 1) void enc_kernel(
    const float* __restrict__ x, const float* __restrict__ eWih,
    const float* __restrict__ eWhh, float* __restrict__ ws)
{
  constexpr int WP = 644;   // w row pad (floats): 4-bank-group tiling floor
  constexpr int XP = 648;   // xh row pad
  __shared__ float wsm[32*WP];
  __shared__ float xh[8*XP];
  __shared__ float zs[8][32];
  const float* ebias = ws + oEbias;
  float* encst = ws + oEncSt;
  float* henc  = ws + oHenc;
  int* ctr = (int*)(ws + oCtr);
  int* abortf = ctr;
  int* slotE = ctr + 1600;

  const int tid = threadIdx.x, bid = blockIdx.x;
  const int q = bid >> 6, j = bid & 63;    // b-group, e-slice
  const int b0 = q*8, e0 = j*8;

  // one-time: stage W slab rows (gate*8+el) -> LDS
  for (int i = tid; i < 32*640; i += 256){
    int r = i / 640, k = i - r*640;
    int gate = r >> 3, el = r & 7;
    int grow = gate*kHE + e0 + el;
    float v = (k < kF) ? eWih[(size_t)grow*kF + k] : eWhh[(size_t)grow*kHE + (k - kF)];
    wsm[r*WP + k] = v;
  }
  const int b_l = tid >> 5, row = tid & 31;       // dot role: (batch, w-row)
  const float biasr = ebias[(row>>3)*kHE + e0 + (row&7)];
  // pointwise role (tid<64): (b_p, e_p)
  const int b_p = tid >> 3, e_p = tid & 7;
  float creg = 0.f;
  __syncthreads();

  int p = 0;
  for (int t = 0; t < kT; ++t){
    // stage x_t for 8 batches (independent of h)
    if (tid < 256){
      int bl2 = tid >> 5, q4 = tid & 31;
      *(float4*)(&xh[bl2*XP + 4*q4]) = ((const float4*)(x + ((size_t)(b0+bl2)*kT + t)*kF))[q4];
    }
    wait_slots(slotE + q*64, 64, t, abortf);
    // stage h_{t-1} for 8 batches via MALL-coherent loads
    #pragma unroll
    for (int i = 0; i < 4; ++i){
      int idx = tid + 256*i;
      int bl2 = idx >> 7, q4 = idx & 127;
      const float* hsrc = henc + (size_t)p*kB*kHE + (size_t)(b0+bl2)*kHE + 4*q4;
      float4 hv;
      hv.x = ld_na(hsrc); hv.y = ld_na(hsrc+1); hv.z = ld_na(hsrc+2); hv.w = ld_na(hsrc+3);
      *(float4*)(&xh[bl2*XP + kF + 4*q4]) = hv;
    }
    __syncthreads();
    // dot: thread (b_l, row): z = w[row] . xh[b_l] over 640
    {
      const float4* wr = (const float4*)(&wsm[row*WP]);
      const float4* xr = (const float4*)(&xh[b_l*XP]);
      float a0=0.f, a1=0.f, a2=0.f, a3=0.f;
      #pragma unroll 8
      for (int kq = 0; kq < 160; ++kq){
        float4 w = wr[kq], v = xr[kq];
        a0 += w.x*v.x; a1 += w.y*v.y; a2 += w.z*v.z; a3 += w.w*v.w;
      }
      zs[b_l][row] = (a0+a1)+(a2+a3) + biasr;
    }
    __syncthreads();
    if (tid < 64){
      float zi = zs[b_p][0*8 + e_p];
      float zf = zs[b_p][1*8 + e_p];
      float zg = zs[b_p][2*8 + e_p];
      float zo = zs[b_p][3*8 + e_p];
      float c2 = fsig(zf)*creg + fsig(zi)*ftanh(zg);
      creg = c2;
      float h = fsig(zo)*ftanh(c2);
      int b = b0 + b_p, e = e0 + e_p;
      st_na(&henc[(size_t)(p^1)*kB*kHE + (size_t)b*kHE + e], h);
      encst[((size_t)b*kT + t)*kHE + e] = h;   // plain; published at kernel end
    }
    stamp_slot(&slotE[q*64 + j], t+1);
    p ^= 1;
  }
}

// ================= kernel 3: enc_proj = enc_states @ Wenc^T + b =================
__global__ __launch_bounds__(256) void encproj_kernel(
    const float* __restrict__ WencW, const float* __restrict__ WencB,
    float* __restrict__ ws)
{
  const float* encst = ws + oEncSt;
  float* encpr = ws + oEncPr;
  __shared__ float4 et[32][32];
  const int tid = threadIdx.x, bid = blockIdx.x;
  const int r0 = bid*32;
  float acc[32];
  #pragma unroll
  for (int i=0;i<32;++i) acc[i]=0.f;
  for (int kt=0; kt<4; ++kt){
    #pragma unroll
    for (int i2=0;i2<4;++i2){
      int q = tid + i2*256;
      int row = q>>5, qi = q&31;
      et[row][qi] = ((const float4*)(encst + ((size_t)(r0+row))*kHE + kt*128))[qi];
    }
    __syncthreads();
    const float4* wv = (const float4*)(WencW + (size_t)tid*kHE + kt*128);
    #pragma unroll 1
    for (int q=0;q<32;++q){
      float4 w = wv[q];
      #pragma unroll
      for (int i=0;i<32;++i){
        float4 e4 = et[i][q];
        acc[i] += e4.x*w.x + e4.y*w.y + e4.z*w.z + e4.w*w.w;
      }
    }
    __syncthreads();
  }
  float bb = WencB[tid];
  #pragma unroll
  for (int i=0;i<32;++i) encpr[((size_t)(r0+i))*kA + tid] = acc[i] + bb;
}

// ================= kernel 4: decoder — 512 blocks, slot-flag sync =================
namespace {
struct SA  { float h[32]; float sc[256]; float lw[32]; };
struct SC  { f16 xt[16][264]; float zb[128][2]; };
struct SmemDec {
  f16 epr[32][272];
  f16 est2[32][516];
  float v[256];
  union { SA a; SC c; } u;
};
}

__global__ __launch_bounds__(256, 2) void dec_kernel(
    const float* __restrict__ Vw, float* __restrict__ out, float* __restrict__ ws)
{
  __shared__ SmemDec sm;
  const int tid = threadIdx.x, bid = blockIdx.x;
  const f16* wdecc = (const f16*)(ws + oWdecC);
  const f16* wdwh  = (const f16*)(ws + oWdWH);
  const float* encst = ws + oEncSt;
  const float* encpr = ws + oEncPr;
  float* hdec = ws + oHdec;
  float* ctxb = ws + oCtx;
  float* den  = ws + oDen;
  float* scp  = ws + oScp;
  const float* dbias = ws + oDbias;
  const float* ab2w  = ws + oAb2;
  int* ctr   = (int*)(ws + oCtr);
  int* abortf = ctr;
  int* slotC = ctr + 64;     // [2][256] by (half, ecp)
  int* slotA = ctr + 576;    // [32][16] by (b, tc)
  int* slotB = ctr + 1088;   // [32][16] by (b, tc)

  const int bA = bid >> 4, tc = bid & 15, t0a = tc*32;      // A/B role
  const int half = bid >> 8, ecp = bid & 255, e0c = ecp*2;  // C role
  const int col_l = tid & 127, ksC = tid >> 7;
  const int e_lC = col_l & 1, gateC = (col_l>>1)&3, b_lC = col_l>>3;
  const int colC = gateC*kHD + e0c + e_lC;
  const f16* wrC = wdecc + (size_t)colC*1024;
  const int rowS = tid>>4, c16 = (tid&15)*16;

  // one-time LDS residents
  for (int i=tid; i<32*256; i+=256){
    int rr = i>>8, c = i&255;
    sm.epr[rr][c] = (f16)encpr[((size_t)bA*kT + t0a + rr)*kA + c];
  }
  for (int i=tid; i<32*512; i+=256){
    int rr = i>>9, c = i&511;
    sm.est2[rr][c] = (f16)encst[((size_t)bA*kT + t0a + rr)*kHE + c];
  }
  sm.v[tid] = Vw[tid];
  const float ab2r = ab2w[tid];
  float cregD=0, dbi=0, dbf=0, dbg=0, dbo=0;
  if (tid < 32){
    int e = e0c + (tid&1);
    dbi = dbias[e]; dbf = dbias[512+e]; dbg = dbias[1024+e]; dbo = dbias[1536+e];
    cregD = fsig(dbi)*ftanh(dbg);
  }
  __syncthreads();

  int r = 0;
  for (int t=0; t<kT; ++t){
    const int rn = (r==2) ? 0 : r+1;
    // ---- A: wait h producers (16 slots = 1 line), dscore partial ----
    wait_slots(slotC + (bA>>4)*256 + tc*16, 16, t, abortf);
    if (tid < 32) sm.u.a.h[tid] = ld_na(hdec + (size_t)r*kB*kHD + (size_t)bA*kHD + t0a + tid);
    __syncthreads();
    {
      const h4* wv = (const h4*)(wdwh + (size_t)tid*kHD + t0a);
      float sp = 0.f;
      #pragma unroll
      for (int q=0;q<8;++q){
        h4 w = wv[q];
        sp += (float)w.x*sm.u.a.h[q*4+0] + (float)w.y*sm.u.a.h[q*4+1]
            + (float)w.z*sm.u.a.h[q*4+2] + (float)w.w*sm.u.a.h[q*4+3];
      }
      st_na(&scp[((size_t)bA*16 + tc)*kA + tid], sp);
    }
    stamp_slot(&slotA[bA*16 + tc], t+1);
    // ---- B: wait 16 dscore partials, tanh-logits, exp, ctx partial ----
    wait_slots(slotA + bA*16, 16, t+1, abortf);
    {
      float sc = ab2r;
      #pragma unroll
      for (int j=0;j<16;++j) sc += ld_na(&scp[((size_t)bA*16 + j)*kA + tid]);
      sm.u.a.sc[tid] = sc;
    }
    __syncthreads();
    {
      const int tl = tid>>3, as = tid&7;
      float acc = 0.f;
      #pragma unroll
      for (int q=0;q<8;++q){
        int a0 = q*32 + as*4;
        h4 e4 = *(const h4*)(&sm.epr[tl][a0]);
        acc += sm.v[a0+0]*ftanh((float)e4.x + sm.u.a.sc[a0+0]);
        acc += sm.v[a0+1]*ftanh((float)e4.y + sm.u.a.sc[a0+1]);
        acc += sm.v[a0+2]*ftanh((float)e4.z + sm.u.a.sc[a0+2]);
        acc += sm.v[a0+3]*ftanh((float)e4.w + sm.u.a.sc[a0+3]);
      }
      acc += __shfl_down(acc, 4, 8);
      acc += __shfl_down(acc, 2, 8);
      acc += __shfl_down(acc, 1, 8);
      if (as == 0) sm.u.a.lw[tl] = __expf(acc) * kScale;
    }
    __syncthreads();
    {
      const int e0p = 2*tid;
      float c0=0.f, c1=0.f;
      #pragma unroll 8
      for (int j=0;j<32;++j){
        float w = sm.u.a.lw[j];
        h2 ev = *(const h2*)(&sm.est2[j][e0p]);
        c0 += w*(float)ev.x; c1 += w*(float)ev.y;
      }
      float* cdst = ctxb + (size_t)r*kB*kHE + (size_t)bA*kHE;
      atomicAdd(&cdst[e0p], c0);
      atomicAdd(&cdst[e0p+1], c1);
      if (tid == 0){
        float ds = 0.f;
        #pragma unroll
        for (int j=0;j<32;++j) ds += sm.u.a.lw[j];
        atomicAdd(&den[r*kB + bA], ds);
      }
      // zero rotation slice rn (last read at t-2): this block zeroes its own t-chunk columns
      if (tid < 32) st_na(ctxb + (size_t)rn*kB*kHE + (size_t)bA*kHE + t0a + tid, 0.f);
      if (tid == 0 && tc == 0) st_na(&den[rn*kB + bA], 0.f);
    }
    stamp_slot(&slotB[bA*16 + tc], t+1);
    // ---- C: wait all 256 ctx partials of this half, LSTM cell ----
    wait_slots(slotB + half*256, 256, t+1, abortf);
    {
      const float rv = frcp(ld_na(&den[r*kB + half*16 + b_lC]));
      float accc=0.f, acch=0.f;
      for (int kc=0; kc<4; ++kc){
        const float* src = ((kc<2) ? (ctxb + (size_t)r*kB*kHE) : (hdec + (size_t)r*kB*kHD))
                           + (size_t)(half*16 + rowS)*512 + (kc&1)*256 + c16;
        float f[16];
        #pragma unroll
        for (int j=0;j<16;++j) f[j] = ld_na(src+j);
        #pragma unroll
        for (int g=0; g<4; ++g){
          h4 hv; hv.x=(f16)f[4*g]; hv.y=(f16)f[4*g+1]; hv.z=(f16)f[4*g+2]; hv.w=(f16)f[4*g+3];
          *(h4*)(&sm.u.c.xt[rowS][c16 + 4*g]) = hv;
        }
        __syncthreads();
        const h4* wc = (const h4*)(wrC) + kc*64 + ksC*32;
        const h4* xv = (const h4*)(&sm.u.c.xt[b_lC][ksC*128]);
        float a = 0.f;
        #pragma unroll 8
        for (int q=0;q<32;++q){
          h4 w = wc[q], v = xv[q];
          a = fdot2(h2{w.x,w.y}, h2{v.x,v.y}, a);
          a = fdot2(h2{w.z,w.w}, h2{v.z,v.w}, a);
        }
        if (kc < 2) accc += a; else acch += a;
        __syncthreads();
      }
      sm.u.c.zb[col_l][ksC] = accc*rv + acch;
      __syncthreads();
      if (tid < 32){
        int base = (tid>>1)*8 + (tid&1);
        int e = e0c + (tid&1), b2 = half*16 + (tid>>1);
        float zi = sm.u.c.zb[base+0][0] + sm.u.c.zb[base+0][1] + dbi;
        float zf = sm.u.c.zb[base+2][0] + sm.u.c.zb[base+2][1] + dbf;
        float zg = sm.u.c.zb[base+4][0] + sm.u.c.zb[base+4][1] + dbg;
        float zo = sm.u.c.zb[base+6][0] + sm.u.c.zb[base+6][1] + dbo;
        float c2 = fsig(zf)*cregD + fsig(zi)*ftanh(zg);
        cregD = c2;
        float h = fsig(zo)*ftanh(c2);
        st_na(&hdec[(size_t)rn*kB*kHD + (size_t)b2*kHD + e], h);
        out[((size_t)b2*kT + t)*kHD + e] = h;
      }
    }
    stamp_slot(&slotC[half*256 + ecp], t+1);
    r = rn;
  }
}

extern "C" void kernel_launch(void* const* d_in, const int* in_sizes, int n_in,
                              void* d_out, int out_size, void* d_ws, size_t ws_size,
                              hipStream_t stream) {
  (void)in_sizes; (void)n_in; (void)out_size; (void)ws_size; // needs ws >= ~56 MB
  const float* x     = (const float*)d_in[0];
  const float* eWih  = (const float*)d_in[1];
  const float* eWhh  = (const float*)d_in[2];
  const float* eBih  = (const float*)d_in[3];
  const float* eBhh  = (const float*)d_in[4];
  const float* WencW = (const float*)d_in[5];
  const float* WencB = (const float*)d_in[6];
  const float* WdecW = (const float*)d_in[7];
  const float* WdecB = (const float*)d_in[8];
  const float* Vw    = (const float*)d_in[9];
  const float* attnB = (const float*)d_in[11];
  const float* dWih  = (const float*)d_in[12];
  const float* dWhh  = (const float*)d_in[13];
  const float* dBih  = (const float*)d_in[14];
  const float* dBhh  = (const float*)d_in[15];
  float* ws = (float*)d_ws;
  int* ctr = (int*)(ws + oCtr);
  hipMemsetAsync(ctr, 0, 8192, stream);
  hipLaunchKernelGGL(init_kernel, dim3(512), dim3(256), 0, stream,
                     eBih, eBhh, WdecW, WdecB, attnB, dWih, dWhh, dBih, dBhh, ws);
  hipLaunchKernelGGL(enc_kernel, dim3(256), dim3(256), 0, stream, x, eWih, eWhh, ws);
  hipLaunchKernelGGL(encproj_kernel, dim3(512), dim3(256), 0, stream, WencW, WencB, ws);
  hipLaunchKernelGGL(dec_kernel, dim3(512), dim3(256), 0, stream, Vw, (float*)d_out, ws);
}